// Round 20
// baseline (132.023 us; speedup 1.0000x reference)
//
#include <hip/hip_runtime.h>

#define Bn 8
#define Vn 3
#define Hn 512
#define Wn 640
#define Nn (Hn * Wn)
#define PX 16                     // pixels per thread (16 divides 640: no row wrap)
#define TPB 256
#define XBLKS (Nn / (TPB * PX))   // 80
#define GRIDN (XBLKS * Vn * Bn)   // 1920 blocks = 7.5/CU -> fully resident

struct __attribute__((aligned(4))) fpair { float a, b; };

__device__ __forceinline__ float rfl(float x) {
    return __int_as_float(__builtin_amdgcn_readfirstlane(__float_as_int(x)));
}

// Inline P = K * RT_j * inv(RT_i) * inv(K), rows 0..2, analytic affine inverses
// (inv([R|t]) = [R^T | -R^T t]; Kinv analytic). Bottom row of P is exactly
// [0,0,0,1] -> reference's divide-by-proj[3] is a no-op; skip row 3.
// Validated R10..R19: absmax 0.0 vs reference's numerical inverses.
__device__ __forceinline__ void computeQ(const float* __restrict__ K,
                                         const float* __restrict__ RT,
                                         int b, int i, float Q[Vn][12]) {
    const float* Kb = K + (size_t)b * 16;
    const float f  = Kb[0], cx = Kb[2], cy = Kb[6];
    const float rf = 1.0f / f;
    const float* Ti = RT + (size_t)(b * Vn + i) * 16;
    const float A00=Ti[0], A01=Ti[1], A02=Ti[2],  A03=Ti[3];
    const float A10=Ti[4], A11=Ti[5], A12=Ti[6],  A13=Ti[7];
    const float A20=Ti[8], A21=Ti[9], A22=Ti[10], A23=Ti[11];
    const float I00=A00, I01=A10, I02=A20, I03=-(A00*A03 + A10*A13 + A20*A23);
    const float I10=A01, I11=A11, I12=A21, I13=-(A01*A03 + A11*A13 + A21*A23);
    const float I20=A02, I21=A12, I22=A22, I23=-(A02*A03 + A12*A13 + A22*A23);
    #pragma unroll
    for (int j = 0; j < Vn; ++j) {
        const float* Tj = RT + (size_t)(b * Vn + j) * 16;
        const float B00=Tj[0], B01=Tj[1], B02=Tj[2],  B03=Tj[3];
        const float B10=Tj[4], B11=Tj[5], B12=Tj[6],  B13=Tj[7];
        const float B20=Tj[8], B21=Tj[9], B22=Tj[10], B23=Tj[11];
        const float M00=B00*I00+B01*I10+B02*I20, M01=B00*I01+B01*I11+B02*I21,
                    M02=B00*I02+B01*I12+B02*I22, M03=B00*I03+B01*I13+B02*I23+B03;
        const float M10=B10*I00+B11*I10+B12*I20, M11=B10*I01+B11*I11+B12*I21,
                    M12=B10*I02+B11*I12+B12*I22, M13=B10*I03+B11*I13+B12*I23+B13;
        const float M20=B20*I00+B21*I10+B22*I20, M21=B20*I01+B21*I11+B22*I21,
                    M22=B20*I02+B21*I12+B22*I22, M23=B20*I03+B21*I13+B22*I23+B23;
        const float G00=f*M00+cx*M20, G01=f*M01+cx*M21, G02=f*M02+cx*M22, G03=f*M03+cx*M23;
        const float G10=f*M10+cy*M20, G11=f*M11+cy*M21, G12=f*M12+cy*M22, G13=f*M13+cy*M23;
        const float G20=M20,          G21=M21,          G22=M22,          G23=M23;
        Q[j][0]  = rfl(G00*rf);  Q[j][1]  = rfl(G01*rf);
        Q[j][2]  = rfl(G02 - (cx*rf)*G00 - (cy*rf)*G01);  Q[j][3]  = rfl(G03);
        Q[j][4]  = rfl(G10*rf);  Q[j][5]  = rfl(G11*rf);
        Q[j][6]  = rfl(G12 - (cx*rf)*G10 - (cy*rf)*G11);  Q[j][7]  = rfl(G13);
        Q[j][8]  = rfl(G20*rf);  Q[j][9]  = rfl(G21*rf);
        Q[j][10] = rfl(G22 - (cx*rf)*G20 - (cy*rf)*G21);  Q[j][11] = rfl(G23);
    }
}

// ---------- Main: ONE branch per pixel, 6 batched paired gathers ----------
__global__ __launch_bounds__(TPB, 8) void loss_main_kernel(const float* __restrict__ pred,
                                                           const float* __restrict__ K,
                                                           const float* __restrict__ RT,
                                                           float* __restrict__ part) {
    // b = blockIdx.x % 8: XCD-batch L2 locality (one batch's 3 planes = 3.93 MB).
    const int id   = blockIdx.x;
    const int b    = id & 7;
    const int r    = id >> 3;
    const int i    = r % Vn;
    const int xblk = r / Vn;

    float Q[Vn][12];
    computeQ(K, RT, b, i, Q);

    // LOAD-BALANCE TRANSPOSE: thread's 16-px segment index p = tid*XBLKS + xblk.
    const int p    = threadIdx.x * XBLKS + xblk;
    const int base = p * PX;
    const int yrow = base / Wn;
    const int xcol = base - yrow * Wn;   // 640/16=40 segments/row: no row wrap
    const float fy = (float)yrow;

    const float* dbase = pred + (size_t)(b * Vn + i) * Nn + base;

    const float cW = (float)Wn / (float)(Wn - 1);   // ix = X*cW - 0.5
    const float cH = (float)Hn / (float)(Hn - 1);

    // per-row (fy) constants per pair
    float rx[Vn], ry[Vn], rz[Vn];
    #pragma unroll
    for (int j = 0; j < Vn; ++j) {
        rx[j] = fmaf(Q[j][1], fy, Q[j][2]);
        ry[j] = fmaf(Q[j][5], fy, Q[j][6]);
        rz[j] = fmaf(Q[j][9], fy, Q[j][10]);
    }

    float num[Vn] = {0.0f, 0.0f, 0.0f};
    float den[Vn] = {0.0f, 0.0f, 0.0f};

    #pragma unroll
    for (int half = 0; half < 2; ++half) {
        float dv[8];
        {
            const float4 a0 = *reinterpret_cast<const float4*>(dbase + half * 8);
            const float4 a1 = *reinterpret_cast<const float4*>(dbase + half * 8 + 4);
            dv[0]=a0.x; dv[1]=a0.y; dv[2]=a0.z; dv[3]=a0.w;
            dv[4]=a1.x; dv[5]=a1.y; dv[6]=a1.z; dv[7]=a1.w;
        }
        #pragma unroll
        for (int k = 0; k < 8; ++k) {
            const float d  = dv[k];
            const float fx = (float)(xcol + half * 8 + k);

            float Za[Vn];
            bool  ia[Vn];
            float ixa[Vn], iya[Vn];
            #pragma unroll
            for (int j = 0; j < Vn; ++j) {
                const float X = fmaf(d, fmaf(Q[j][0], fx, rx[j]), Q[j][3]);
                const float Y = fmaf(d, fmaf(Q[j][4], fx, ry[j]), Q[j][7]);
                Za[j] = fmaf(d, fmaf(Q[j][8], fx, rz[j]), Q[j][11]);
                ia[j] = (X >= 0.0f) & (X <= (float)(Wn - 1)) &
                        (Y >= 0.0f) & (Y <= (float)(Hn - 1));
                ixa[j] = fmaf(X, cW, -0.5f);
                iya[j] = fmaf(Y, cH, -0.5f);
            }

            // ONE branch per pixel (all 3 j's inside -> 6 loads per vmcnt wait)
            if (ia[0] | ia[1] | ia[2]) {
                float wx1a[Vn], wy1a[Vn];
                int   x0a[Vn], y0a[Vn];
                bool  bord = false;
                #pragma unroll
                for (int j = 0; j < Vn; ++j) {
                    const float x0f = floorf(ixa[j]);
                    const float y0f = floorf(iya[j]);
                    wx1a[j] = ixa[j] - x0f;
                    wy1a[j] = iya[j] - y0f;
                    x0a[j] = (int)x0f;
                    y0a[j] = (int)y0f;
                    bord |= ia[j] & ((x0a[j] < 0) | (x0a[j] > Wn - 2) |
                                     (y0a[j] < 0) | (y0a[j] > Hn - 2));
                }

                if (__ballot(bord) == 0ull) {
                    // FAST PATH (~92%): every active (ia) lane interior for its
                    // active j's -> direct addresses, no clamps/corner-selects.
                    int ad[Vn];
                    #pragma unroll
                    for (int j = 0; j < Vn; ++j)
                        ad[j] = ia[j] ? (y0a[j] * Wn + x0a[j]) : 0;
                    fpair q0[Vn], q1[Vn];
                    #pragma unroll
                    for (int j = 0; j < Vn; ++j) {
                        const float* img = pred + (size_t)(b * Vn + j) * Nn;
                        q0[j] = *reinterpret_cast<const fpair*>(img + ad[j]);
                        q1[j] = *reinterpret_cast<const fpair*>(img + ad[j] + Wn);
                    }
                    #pragma unroll
                    for (int j = 0; j < Vn; ++j) {
                        const float wx1 = wx1a[j], wy1 = wy1a[j];
                        const float wx0 = 1.0f - wx1, wy0 = 1.0f - wy1;
                        const float wx0v = ia[j] ? wx0 : 0.0f;   // !ia lanes: inner=0
                        const float wx1v = ia[j] ? wx1 : 0.0f;
                        const float warped = wy0 * fmaf(wx0v, q0[j].a, wx1v * q0[j].b)
                                           + wy1 * fmaf(wx0v, q1[j].a, wx1v * q1[j].b);
                        const float Zs = ia[j] ? Za[j] : 0.0f;
                        num[j] += fabsf(warped - Zs);
                        den[j] += ia[j] ? 1.0f : 0.0f;
                    }
                } else {
                    // SLOW PATH: R10's verified masked/clamped form (absmax 0.0)
                    int  r0[Vn], r1[Vn];
                    bool xlo[Vn], xhi[Vn];
                    #pragma unroll
                    for (int j = 0; j < Vn; ++j) {
                        const int y1 = y0a[j] + 1;
                        const int cx2 = min(max(x0a[j], 0), Wn - 2);
                        const int cy0 = min(max(y0a[j], 0), Hn - 1);
                        const int cy1 = min(max(y1, 0), Hn - 1);
                        r0[j] = cy0 * Wn + cx2;
                        r1[j] = cy1 * Wn + cx2;
                        xlo[j] = (x0a[j] >= 0);
                        xhi[j] = (x0a[j] <= Wn - 2);
                    }
                    fpair q0[Vn], q1[Vn];
                    #pragma unroll
                    for (int j = 0; j < Vn; ++j) {
                        const float* img = pred + (size_t)(b * Vn + j) * Nn;
                        q0[j] = *reinterpret_cast<const fpair*>(img + r0[j]);
                        q1[j] = *reinterpret_cast<const fpair*>(img + r1[j]);
                    }
                    #pragma unroll
                    for (int j = 0; j < Vn; ++j) {
                        const float wx1 = wx1a[j], wy1 = wy1a[j];
                        const float wx0 = 1.0f - wx1, wy0 = 1.0f - wy1;
                        const float c00 = xhi[j] ? q0[j].a : q0[j].b;
                        const float c10 = xlo[j] ? q0[j].b : q0[j].a;
                        const float c01 = xhi[j] ? q1[j].a : q1[j].b;
                        const float c11 = xlo[j] ? q1[j].b : q1[j].a;
                        const bool inb = ia[j];
                        const float wx0v = (inb && xlo[j])            ? wx0 : 0.0f;
                        const float wx1v = (inb && (x0a[j] + 1 < Wn)) ? wx1 : 0.0f;
                        const float wy0v = (inb && (y0a[j] >= 0))     ? wy0 : 0.0f;
                        const float wy1v = (inb && (y0a[j] + 1 < Hn)) ? wy1 : 0.0f;
                        const float warped = wy0v * fmaf(wx0v, c00, wx1v * c10)
                                           + wy1v * fmaf(wx0v, c01, wx1v * c11);
                        const float Zs = inb ? Za[j] : 0.0f;
                        num[j] += fabsf(warped - Zs);
                        den[j] += inb ? 1.0f : 0.0f;
                    }
                }
            }
        }
    }

    // wave-64 shuffle reduction over 6 independent accumulators
    #pragma unroll
    for (int off = 32; off > 0; off >>= 1) {
        #pragma unroll
        for (int j = 0; j < Vn; ++j) {
            num[j] += __shfl_down(num[j], off, 64);
            den[j] += __shfl_down(den[j], off, 64);
        }
    }
    __shared__ float s_red[4][2 * Vn];
    const int lane = threadIdx.x & 63;
    const int wid  = threadIdx.x >> 6;
    if (lane == 0) {
        #pragma unroll
        for (int j = 0; j < Vn; ++j) {
            s_red[wid][2 * j + 0] = num[j];
            s_red[wid][2 * j + 1] = den[j];
        }
    }
    __syncthreads();
    // per-block partial store: no init needed, no atomics, no fence
    if (threadIdx.x < 2 * Vn) {
        const int slot = threadIdx.x;
        const float v = s_red[0][slot] + s_red[1][slot] + s_red[2][slot] + s_red[3][slot];
        part[(size_t)id * 8 + slot] = v;
    }
}

// ---------- Finalize: sum 1920 partials -> 9 pair accums -> total ----------
__global__ __launch_bounds__(TPB) void finalize_kernel(const float* __restrict__ part,
                                                       float* __restrict__ out) {
    float acc[2 * Vn * Vn];   // [pair*2 + comp], pair = i*3+j
    #pragma unroll
    for (int s = 0; s < 2 * Vn * Vn; ++s) acc[s] = 0.0f;

    for (int m = threadIdx.x; m < GRIDN; m += TPB) {
        const int i = (m >> 3) % Vn;
        const float* pp = part + (size_t)m * 8;
        #pragma unroll
        for (int j = 0; j < Vn; ++j) {
            acc[(i * Vn + j) * 2 + 0] += pp[2 * j + 0];
            acc[(i * Vn + j) * 2 + 1] += pp[2 * j + 1];
        }
    }
    #pragma unroll
    for (int off = 32; off > 0; off >>= 1) {
        #pragma unroll
        for (int s = 0; s < 2 * Vn * Vn; ++s)
            acc[s] += __shfl_down(acc[s], off, 64);
    }
    __shared__ float s_fin[4][2 * Vn * Vn];
    const int lane = threadIdx.x & 63;
    const int wid  = threadIdx.x >> 6;
    if (lane == 0) {
        #pragma unroll
        for (int s = 0; s < 2 * Vn * Vn; ++s) s_fin[wid][s] = acc[s];
    }
    __syncthreads();
    if (threadIdx.x == 0) {
        float t = 0.0f;
        #pragma unroll
        for (int pr = 0; pr < Vn * Vn; ++pr) {
            const float nn = s_fin[0][pr*2+0] + s_fin[1][pr*2+0] + s_fin[2][pr*2+0] + s_fin[3][pr*2+0];
            const float dd = s_fin[0][pr*2+1] + s_fin[1][pr*2+1] + s_fin[2][pr*2+1] + s_fin[3][pr*2+1];
            t += nn / fmaxf(dd, 1.0f);
        }
        out[0] = t;
    }
}

extern "C" void kernel_launch(void* const* d_in, const int* in_sizes, int n_in,
                              void* d_out, int out_size, void* d_ws, size_t ws_size,
                              hipStream_t stream) {
    const float* pred = (const float*)d_in[0];   // (B,V,H,W)
    const float* K    = (const float*)d_in[1];   // (B,4,4)
    const float* RT   = (const float*)d_in[2];   // (B,V,4,4)
    float* out = (float*)d_out;

    float* part = (float*)d_ws;                  // GRIDN*8 floats, fully overwritten

    loss_main_kernel<<<GRIDN, TPB, 0, stream>>>(pred, K, RT, part);
    finalize_kernel<<<1, TPB, 0, stream>>>(part, out);
}

// Round 21
// 110.638 us; speedup vs baseline: 1.1933x; 1.1933x over previous
//
#include <hip/hip_runtime.h>

#define Bn 8
#define Vn 3
#define Hn 512
#define Wn 640
#define Nn (Hn * Wn)
#define PX 16                     // pixels per thread (16 divides 640: no row wrap)
#define TPB 256
#define XBLKS (Nn / (TPB * PX))   // 80
#define GRIDN (XBLKS * Vn * Bn)   // 1920 blocks = 7.5/CU -> fully resident

struct __attribute__((aligned(4))) fpair { float a, b; };

__device__ __forceinline__ float rfl(float x) {
    return __int_as_float(__builtin_amdgcn_readfirstlane(__float_as_int(x)));
}

// Inline P = K * RT_j * inv(RT_i) * inv(K), rows 0..2, analytic affine inverses
// (inv([R|t]) = [R^T | -R^T t]; Kinv analytic). Bottom row of P is exactly
// [0,0,0,1] -> reference's divide-by-proj[3] is a no-op; skip row 3.
// Validated R10..R19: absmax 0.0 vs reference's numerical inverses.
__device__ __forceinline__ void computeQ(const float* __restrict__ K,
                                         const float* __restrict__ RT,
                                         int b, int i, float Q[Vn][12]) {
    const float* Kb = K + (size_t)b * 16;
    const float f  = Kb[0], cx = Kb[2], cy = Kb[6];
    const float rf = 1.0f / f;
    const float* Ti = RT + (size_t)(b * Vn + i) * 16;
    const float A00=Ti[0], A01=Ti[1], A02=Ti[2],  A03=Ti[3];
    const float A10=Ti[4], A11=Ti[5], A12=Ti[6],  A13=Ti[7];
    const float A20=Ti[8], A21=Ti[9], A22=Ti[10], A23=Ti[11];
    const float I00=A00, I01=A10, I02=A20, I03=-(A00*A03 + A10*A13 + A20*A23);
    const float I10=A01, I11=A11, I12=A21, I13=-(A01*A03 + A11*A13 + A21*A23);
    const float I20=A02, I21=A12, I22=A22, I23=-(A02*A03 + A12*A13 + A22*A23);
    #pragma unroll
    for (int j = 0; j < Vn; ++j) {
        const float* Tj = RT + (size_t)(b * Vn + j) * 16;
        const float B00=Tj[0], B01=Tj[1], B02=Tj[2],  B03=Tj[3];
        const float B10=Tj[4], B11=Tj[5], B12=Tj[6],  B13=Tj[7];
        const float B20=Tj[8], B21=Tj[9], B22=Tj[10], B23=Tj[11];
        const float M00=B00*I00+B01*I10+B02*I20, M01=B00*I01+B01*I11+B02*I21,
                    M02=B00*I02+B01*I12+B02*I22, M03=B00*I03+B01*I13+B02*I23+B03;
        const float M10=B10*I00+B11*I10+B12*I20, M11=B10*I01+B11*I11+B12*I21,
                    M12=B10*I02+B11*I12+B12*I22, M13=B10*I03+B11*I13+B12*I23+B13;
        const float M20=B20*I00+B21*I10+B22*I20, M21=B20*I01+B21*I11+B22*I21,
                    M22=B20*I02+B21*I12+B22*I22, M23=B20*I03+B21*I13+B22*I23+B23;
        const float G00=f*M00+cx*M20, G01=f*M01+cx*M21, G02=f*M02+cx*M22, G03=f*M03+cx*M23;
        const float G10=f*M10+cy*M20, G11=f*M11+cy*M21, G12=f*M12+cy*M22, G13=f*M13+cy*M23;
        const float G20=M20,          G21=M21,          G22=M22,          G23=M23;
        Q[j][0]  = rfl(G00*rf);  Q[j][1]  = rfl(G01*rf);
        Q[j][2]  = rfl(G02 - (cx*rf)*G00 - (cy*rf)*G01);  Q[j][3]  = rfl(G03);
        Q[j][4]  = rfl(G10*rf);  Q[j][5]  = rfl(G11*rf);
        Q[j][6]  = rfl(G12 - (cx*rf)*G10 - (cy*rf)*G11);  Q[j][7]  = rfl(G13);
        Q[j][8]  = rfl(G20*rf);  Q[j][9]  = rfl(G21*rf);
        Q[j][10] = rfl(G22 - (cx*rf)*G20 - (cy*rf)*G21);  Q[j][11] = rfl(G23);
    }
}

// ---------- Main: exec-masked gather body, border fast-path, partial stores ----------
__global__ __launch_bounds__(TPB, 8) void loss_main_kernel(const float* __restrict__ pred,
                                                           const float* __restrict__ K,
                                                           const float* __restrict__ RT,
                                                           float* __restrict__ part) {
    // b = blockIdx.x % 8: XCD-batch L2 locality (one batch's 3 planes = 3.93 MB).
    const int id   = blockIdx.x;
    const int b    = id & 7;
    const int r    = id >> 3;
    const int i    = r % Vn;
    const int xblk = r / Vn;

    float Q[Vn][12];
    computeQ(K, RT, b, i, Q);

    // LOAD-BALANCE TRANSPOSE: thread's 16-px segment index p = tid*XBLKS + xblk.
    const int p    = threadIdx.x * XBLKS + xblk;
    const int base = p * PX;
    const int yrow = base / Wn;
    const int xcol = base - yrow * Wn;   // 640/16=40 segments/row: no row wrap
    const float fy = (float)yrow;

    const float* dptr = pred + (size_t)(b * Vn + i) * Nn + base;
    float dv[PX];
    {
        const float4 a0 = *reinterpret_cast<const float4*>(dptr);
        const float4 a1 = *reinterpret_cast<const float4*>(dptr + 4);
        const float4 a2 = *reinterpret_cast<const float4*>(dptr + 8);
        const float4 a3 = *reinterpret_cast<const float4*>(dptr + 12);
        dv[0]=a0.x; dv[1]=a0.y; dv[2]=a0.z; dv[3]=a0.w;
        dv[4]=a1.x; dv[5]=a1.y; dv[6]=a1.z; dv[7]=a1.w;
        dv[8]=a2.x; dv[9]=a2.y; dv[10]=a2.z; dv[11]=a2.w;
        dv[12]=a3.x; dv[13]=a3.y; dv[14]=a3.z; dv[15]=a3.w;
    }

    const float cW = (float)Wn / (float)(Wn - 1);   // ix = X*cW - 0.5
    const float cH = (float)Hn / (float)(Hn - 1);

    float num[Vn] = {0.0f, 0.0f, 0.0f};
    float den[Vn] = {0.0f, 0.0f, 0.0f};

    #pragma unroll
    for (int j = 0; j < Vn; ++j) {
        const float* __restrict__ img = pred + (size_t)(b * Vn + j) * Nn;
        const float rx = fmaf(Q[j][1], fy, Q[j][2]);
        const float ry = fmaf(Q[j][5], fy, Q[j][6]);
        const float rz = fmaf(Q[j][9], fy, Q[j][10]);

        #pragma unroll
        for (int k = 0; k < PX; ++k) {
            const float d  = dv[k];
            const float fx = (float)(xcol + k);

            const float X = fmaf(d, fmaf(Q[j][0], fx, rx), Q[j][3]);
            const float Y = fmaf(d, fmaf(Q[j][4], fx, ry), Q[j][7]);
            const float Z = fmaf(d, fmaf(Q[j][8], fx, rz), Q[j][11]);

            const bool inb = (X >= 0.0f) & (X <= (float)(Wn - 1)) &
                             (Y >= 0.0f) & (Y <= (float)(Hn - 1));
            if (inb) {
                const float ix = fmaf(X, cW, -0.5f);
                const float iy = fmaf(Y, cH, -0.5f);
                const float x0f = floorf(ix);
                const float y0f = floorf(iy);
                const float wx1 = ix - x0f;
                const float wy1 = iy - y0f;
                const float wx0 = 1.0f - wx1;
                const float wy0 = 1.0f - wy1;
                const int x0 = (int)x0f;           // in [-1, W-1]
                const int y0 = (int)y0f;           // in [-1, H-1]
                const bool border = (x0 < 0) | (x0 > Wn - 2) | (y0 < 0) | (y0 > Hn - 2);
                float warped;
                if (__ballot(border) == 0ull) {
                    // FAST PATH (~97% of bodies): all active lanes interior ->
                    // direct addresses, unmasked weights. Bitwise-identical to
                    // the masked path for interior samples.
                    const int ad = y0 * Wn + x0;
                    const fpair q0 = *reinterpret_cast<const fpair*>(img + ad);
                    const fpair q1 = *reinterpret_cast<const fpair*>(img + ad + Wn);
                    warped = wy0 * fmaf(wx0, q0.a, wx1 * q0.b)
                           + wy1 * fmaf(wx0, q1.a, wx1 * q1.b);
                } else {
                    const int x1 = x0 + 1;
                    const int y1 = y0 + 1;
                    const int cy0 = max(y0, 0);
                    const int cy1 = min(y1, Hn - 1);
                    const int cx  = min(max(x0, 0), Wn - 2);
                    const bool xlo = (x0 >= 0);
                    const bool xhi = (x0 <= Wn - 2);
                    const fpair q0 = *reinterpret_cast<const fpair*>(img + (cy0 * Wn + cx));
                    const fpair q1 = *reinterpret_cast<const fpair*>(img + (cy1 * Wn + cx));
                    const float c00 = xhi ? q0.a : q0.b;
                    const float c10 = xlo ? q0.b : q0.a;
                    const float c01 = xhi ? q1.a : q1.b;
                    const float c11 = xlo ? q1.b : q1.a;
                    const float wx0v = xlo ? wx0 : 0.0f;
                    const float wx1v = (x1 < Wn) ? wx1 : 0.0f;
                    const float wy0v = (y0 >= 0) ? wy0 : 0.0f;
                    const float wy1v = (y1 < Hn) ? wy1 : 0.0f;
                    warped = wy0v * fmaf(wx0v, c00, wx1v * c10)
                           + wy1v * fmaf(wx0v, c01, wx1v * c11);
                }
                num[j] += fabsf(warped - Z);
                den[j] += 1.0f;
            }
        }
    }

    // wave-64 shuffle reduction over 6 independent accumulators
    #pragma unroll
    for (int off = 32; off > 0; off >>= 1) {
        #pragma unroll
        for (int j = 0; j < Vn; ++j) {
            num[j] += __shfl_down(num[j], off, 64);
            den[j] += __shfl_down(den[j], off, 64);
        }
    }
    __shared__ float s_red[4][2 * Vn];
    const int lane = threadIdx.x & 63;
    const int wid  = threadIdx.x >> 6;
    if (lane == 0) {
        #pragma unroll
        for (int j = 0; j < Vn; ++j) {
            s_red[wid][2 * j + 0] = num[j];
            s_red[wid][2 * j + 1] = den[j];
        }
    }
    __syncthreads();
    // per-block partial store: no init needed, no atomics, no fence
    if (threadIdx.x < 2 * Vn) {
        const int slot = threadIdx.x;
        const float v = s_red[0][slot] + s_red[1][slot] + s_red[2][slot] + s_red[3][slot];
        part[(size_t)id * 8 + slot] = v;
    }
}

// ---------- Finalize: sum 1920 partials -> 9 pair accums -> total ----------
__global__ __launch_bounds__(TPB) void finalize_kernel(const float* __restrict__ part,
                                                       float* __restrict__ out) {
    float acc[2 * Vn * Vn];   // [pair*2 + comp], pair = i*3+j
    #pragma unroll
    for (int s = 0; s < 2 * Vn * Vn; ++s) acc[s] = 0.0f;

    for (int m = threadIdx.x; m < GRIDN; m += TPB) {
        const int i = (m >> 3) % Vn;
        const float* pp = part + (size_t)m * 8;
        #pragma unroll
        for (int j = 0; j < Vn; ++j) {
            acc[(i * Vn + j) * 2 + 0] += pp[2 * j + 0];
            acc[(i * Vn + j) * 2 + 1] += pp[2 * j + 1];
        }
    }
    #pragma unroll
    for (int off = 32; off > 0; off >>= 1) {
        #pragma unroll
        for (int s = 0; s < 2 * Vn * Vn; ++s)
            acc[s] += __shfl_down(acc[s], off, 64);
    }
    __shared__ float s_fin[4][2 * Vn * Vn];
    const int lane = threadIdx.x & 63;
    const int wid  = threadIdx.x >> 6;
    if (lane == 0) {
        #pragma unroll
        for (int s = 0; s < 2 * Vn * Vn; ++s) s_fin[wid][s] = acc[s];
    }
    __syncthreads();
    if (threadIdx.x == 0) {
        float t = 0.0f;
        #pragma unroll
        for (int pr = 0; pr < Vn * Vn; ++pr) {
            const float nn = s_fin[0][pr*2+0] + s_fin[1][pr*2+0] + s_fin[2][pr*2+0] + s_fin[3][pr*2+0];
            const float dd = s_fin[0][pr*2+1] + s_fin[1][pr*2+1] + s_fin[2][pr*2+1] + s_fin[3][pr*2+1];
            t += nn / fmaxf(dd, 1.0f);
        }
        out[0] = t;
    }
}

extern "C" void kernel_launch(void* const* d_in, const int* in_sizes, int n_in,
                              void* d_out, int out_size, void* d_ws, size_t ws_size,
                              hipStream_t stream) {
    const float* pred = (const float*)d_in[0];   // (B,V,H,W)
    const float* K    = (const float*)d_in[1];   // (B,4,4)
    const float* RT   = (const float*)d_in[2];   // (B,V,4,4)
    float* out = (float*)d_out;

    float* part = (float*)d_ws;                  // GRIDN*8 floats, fully overwritten

    loss_main_kernel<<<GRIDN, TPB, 0, stream>>>(pred, K, RT, part);
    finalize_kernel<<<1, TPB, 0, stream>>>(part, out);
}